// Round 8
// baseline (566.059 us; speedup 1.0000x reference)
//
#include <hip/hip_runtime.h>
#include <hip/hip_fp16.h>
#include <math.h>

// Problem constants (fixed by the reference)
#define BN_NODES 16384     // B*N
#define DIM 128            // D
#define HID 256            // H
#define TK 2048            // distance-table knots
#define TRANGE 32.0f
#define TSTEP (TRANGE / (float)TK)   // 1/64
#define TINV  ((float)TK / TRANGE)   // 64
#define LN_EPS 1e-5f
#define EPB 4096           // edges per block in binA

typedef _Float16 f16x8 __attribute__((ext_vector_type(8)));
typedef __attribute__((ext_vector_type(4))) float f32x4;
typedef __attribute__((ext_vector_type(8))) unsigned short ushort8v;

__device__ __forceinline__ unsigned short f2h(float f) {
    _Float16 h = (_Float16)f;          // v_cvt_f16_f32, RNE
    return *(unsigned short*)&h;
}
__device__ __forceinline__ __half2 u2h2(unsigned int u) {
    union { unsigned int u; __half2 h; } c; c.u = u; return c.h;
}

// ---------------------------------------------------------------------------
// K1 "prep": blocks 0..255 build the interleaved fp16 filter table
//   Tb2[k][pair p] = (A_{2p}, A_{2p+1}, D_{2p}, D_{2p+1})  where A = T[k],
//   D = T[k+1]-T[k]  -> ONE dwordx2 gather per edge-lane does full interp.
// 256..319 transpose W3 -> w3t[n][k] fp16; 320..351 W4 -> w4t[n][k];
// 352..1375 h -> xh fp16; 1376.. histogram of row nodes.
__global__ __launch_bounds__(256) void prep_kernel(
        const float* __restrict__ W1, const float* __restrict__ b1,
        const float* __restrict__ W2, const float* __restrict__ b2,
        const float* __restrict__ W3, const float* __restrict__ W4,
        const float* __restrict__ h, const int* __restrict__ ei,
        unsigned short* __restrict__ Tb2, unsigned short* __restrict__ w3t,
        unsigned short* __restrict__ w4t, unsigned short* __restrict__ xh,
        int* __restrict__ counts, int nE) {
    __shared__ float smem[9 * 256 + 9 * 128];   // 13.5 KB, role-dependent
    int bid = blockIdx.x, t = threadIdx.x;
    if (bid < 256) {
        float* a    = smem;            // [9][256]  (knots k0..k0+8 incl. boundary)
        float* part = smem + 9 * 256;  // [9][128]
        int k0 = bid * 8;
        float w1 = W1[t], bb = b1[t];
#pragma unroll
        for (int k = 0; k < 9; ++k) {
            float dist = (float)(k0 + k) * TSTEP;
            float z = dist * w1 + bb;
            a[k * 256 + t] = z / (1.0f + expf(-z));
        }
        __syncthreads();
        int hg = t >> 7, d = t & 127;
        float acc[9] = {0.f,0.f,0.f,0.f,0.f,0.f,0.f,0.f,0.f};
        for (int hh = 0; hh < 128; ++hh) {
            int hidx = hg * 128 + hh;
            float w = W2[hidx * DIM + d];
#pragma unroll
            for (int k = 0; k < 9; ++k) acc[k] += a[k * 256 + hidx] * w;
        }
        if (hg == 1) {
#pragma unroll
            for (int k = 0; k < 9; ++k) part[k * 128 + d] = acc[k];
        }
        __syncthreads();
        if (hg == 0) {
            float bd = b2[d];
            float v[9];
#pragma unroll
            for (int k = 0; k < 9; ++k) v[k] = acc[k] + part[k * 128 + d] + bd;
#pragma unroll
            for (int k = 0; k < 8; ++k) {
                unsigned int base = (unsigned int)(k0 + k) * 256u + (unsigned int)((d >> 1) * 4 + (d & 1));
                Tb2[base]     = f2h(v[k]);              // value
                Tb2[base + 2] = f2h(v[k + 1] - v[k]);   // delta
            }
        }
    } else if (bid < 320) {
        float* s = smem;   // [32][33]
        int tid = bid - 256, tr = tid >> 3, tc = tid & 7;
        int lr = t >> 5, lc = t & 31;
#pragma unroll
        for (int rep = 0; rep < 4; ++rep) {
            int k = tr * 32 + rep * 8 + lr, n = tc * 32 + lc;
            s[lc * 33 + rep * 8 + lr] = W3[k * 256 + n];
        }
        __syncthreads();
#pragma unroll
        for (int rep = 0; rep < 4; ++rep) {
            int n = tc * 32 + rep * 8 + lr, k = tr * 32 + lc;
            w3t[n * 256 + k] = f2h(s[(rep * 8 + lr) * 33 + lc]);
        }
    } else if (bid < 352) {
        float* s = smem;
        int tid = bid - 320, tr = tid >> 2, tc = tid & 3;
        int lr = t >> 5, lc = t & 31;
#pragma unroll
        for (int rep = 0; rep < 4; ++rep) {
            int k = tr * 32 + rep * 8 + lr, n = tc * 32 + lc;
            s[lc * 33 + rep * 8 + lr] = W4[k * 128 + n];
        }
        __syncthreads();
#pragma unroll
        for (int rep = 0; rep < 4; ++rep) {
            int n = tc * 32 + rep * 8 + lr, k = tr * 32 + lc;
            w4t[n * 256 + k] = f2h(s[(rep * 8 + lr) * 33 + lc]);
        }
    } else if (bid < 1376) {
        int i0 = (bid - 352) * 2048 + t * 8;
        float4 v0 = *(const float4*)&h[i0];
        float4 v1 = *(const float4*)&h[i0 + 4];
        ushort8v o;
        o[0] = f2h(v0.x); o[1] = f2h(v0.y); o[2] = f2h(v0.z); o[3] = f2h(v0.w);
        o[4] = f2h(v1.x); o[5] = f2h(v1.y); o[6] = f2h(v1.z); o[7] = f2h(v1.w);
        *(ushort8v*)&xh[i0] = o;
    } else {
        int e = (bid - 1376) * 256 + t;
        if (e < nE) atomicAdd(&counts[ei[e]], 1);
    }
}

// ---------------------------------------------------------------------------
// K2: exclusive scan over 16384 counts (1024 threads, 16 each) + bin cursors
__global__ void scan_kernel(const int* __restrict__ counts, int* __restrict__ offsets,
                            int* __restrict__ bin_cursor) {
    __shared__ int s[1024];
    int t = threadIdx.x;
    int base = t * 16;
    int sum = 0;
#pragma unroll
    for (int i = 0; i < 4; ++i) {
        int4 v = *(const int4*)&counts[base + i * 4];
        sum += v.x + v.y + v.z + v.w;
    }
    s[t] = sum;
    __syncthreads();
    for (int off = 1; off < 1024; off <<= 1) {
        int v = (t >= off) ? s[t - off] : 0;
        __syncthreads();
        s[t] += v;
        __syncthreads();
    }
    int run = (t == 0) ? 0 : s[t - 1];
    for (int i = 0; i < 16; ++i) {
        int c = counts[base + i];
        offsets[base + i] = run;
        run += c;
    }
    if (t == 1023) offsets[BN_NODES] = run;
    __syncthreads();
    if (t < 256) bin_cursor[t] = offsets[t * 64];
}

// ---------------------------------------------------------------------------
// K3: bin scatter + edge precompute. LDS counting-sort 4096-edge chunks into
// 256 bins (bin = row>>6); at write-out compute dist -> knot k and fp16 frac,
// emit uint2 (r<<16|c, k<<16|frac_bits) to per-bin staging. (Per-bin bursty
// writes avoid the 13x write amplification of random 4B scatter.)
__global__ __launch_bounds__(256) void binA_kernel(
        const int* __restrict__ ei, const float* __restrict__ x,
        int* __restrict__ bin_cursor, uint2* __restrict__ staging, int nE) {
    __shared__ int cnt[256];
    __shared__ int pre[256];
    __shared__ int gbase[256];
    __shared__ unsigned int rec[EPB];   // 16 KB
    int t = threadIdx.x;
    int e0 = blockIdx.x * EPB;
    int m = min(EPB, nE - e0);
    cnt[t] = 0;
    __syncthreads();
    unsigned int code[16];
    int rk[16], bn[16];
#pragma unroll
    for (int j = 0; j < 16; ++j) {
        int idx = j * 256 + t;
        rk[j] = -1; bn[j] = 0; code[j] = 0;
        if (idx < m) {
            int e = e0 + idx;
            int r = ei[e], c = ei[nE + e];
            code[j] = ((unsigned int)r << 16) | (unsigned int)c;
            bn[j] = r >> 6;
            rk[j] = atomicAdd(&cnt[bn[j]], 1);
        }
    }
    __syncthreads();
    int v = cnt[t];
    pre[t] = v;
    __syncthreads();
    for (int off = 1; off < 256; off <<= 1) {
        int add = (t >= off) ? pre[t - off] : 0;
        __syncthreads();
        pre[t] += add;
        __syncthreads();
    }
    int excl = pre[t] - v;
    __syncthreads();
    pre[t] = excl;
    gbase[t] = atomicAdd(&bin_cursor[t], v);
    __syncthreads();
#pragma unroll
    for (int j = 0; j < 16; ++j)
        if (rk[j] >= 0) rec[pre[bn[j]] + rk[j]] = code[j];
    __syncthreads();
    for (int i = t; i < m; i += 256) {
        unsigned int cd = rec[i];
        int b = (int)(cd >> 22);            // row >> 6
        int r = (int)(cd >> 16);
        int c = (int)(cd & 0xffffu);
        float dx = x[r * 3 + 0] - x[c * 3 + 0];
        float dy = x[r * 3 + 1] - x[c * 3 + 1];
        float dz = x[r * 3 + 2] - x[c * 3 + 2];
        float u = sqrtf(dx * dx + dy * dy + dz * dz) * TINV;
        int k = min((int)u, TK - 2);
        float frac = u - (float)k;
        uint2 o;
        o.x = cd;
        o.y = ((unsigned int)k << 16) | (unsigned int)f2h(frac);
        staging[gbase[b] + (i - pre[b])] = o;
    }
}

// ---------------------------------------------------------------------------
// K4 "mega": bin-grain fusion of binB+agg+node. One block per bin (64 nodes,
// 256 blocks x 1024 threads = 1 block/CU, 16 waves). Phase A: stream the
// bin's staging slice; each wave takes 4 edges at a time; lanes own 2 dims;
// message = hfma2(interp-pair-table) accumulated into LDS fp32 via atomicAdd
// (distinct dwords per lane -> <=2-way bank aliasing = free; no capacity
// limit, no overflow path). Phase B: normalize -> fp16 -> MFMA GEMM1 -> LN
// -> SiLU -> GEMM2 -> out. No erec/aggb global round-trips.
__global__ __launch_bounds__(1024, 4) void agg_node_kernel(
        const uint2* __restrict__ staging, const int* __restrict__ offsets,
        const unsigned short* __restrict__ Tb2, const unsigned short* __restrict__ xh,
        const unsigned short* __restrict__ w3t, const float* __restrict__ b3,
        const float* __restrict__ gamma, const float* __restrict__ beta,
        const unsigned short* __restrict__ w4t, const float* __restrict__ b4,
        float* __restrict__ out) {
    __shared__ float aggf[64 * 128];                        // 32 KB fp32 accum
    __shared__ __align__(16) unsigned short aggh[64][136];  // fp16 agg (272B stride)
    __shared__ __align__(16) unsigned short a_lds[64][264]; // fp16 act (528B stride)
    __shared__ int pref[65];
    __shared__ float part_s[16][64], part_q[16][64];        // 8 KB
    __shared__ float tot_mu[64], tot_rs[64];

    int t = threadIdx.x;
    int bin = blockIdx.x;
    int n0 = bin * 64;
#pragma unroll
    for (int j = 0; j < 8; ++j) aggf[t * 8 + j] = 0.f;
    if (t < 65) pref[t] = offsets[n0 + t];
    __syncthreads();
    int s0 = pref[0];
    int total = pref[64] - s0;

    int wid = t >> 6, lane = t & 63, dd = lane * 2;

    // ---- phase A: streamed LDS-atomic aggregation
    for (int j = wid * 4; j < total; j += 64) {
        int lim = min(4, total - j);
        uint2 e[4];
        for (int jj = 0; jj < lim; ++jj) e[jj] = staging[s0 + j + jj];
        for (int jj = 0; jj < lim; ++jj) {
            int r6 = (int)(e[jj].x >> 16) - n0;
            int c  = (int)(e[jj].x & 0xffffu);
            int k  = (int)(e[jj].y >> 16);
            unsigned int ff = (e[jj].y & 0xffffu) * 0x10001u;
            unsigned int hx = *(const unsigned int*)&xh[c * DIM + dd];
            uint2 tb = *(const uint2*)&Tb2[(k << 8) + lane * 4];
            __half2 filt = __hfma2(u2h2(tb.y), u2h2(ff), u2h2(tb.x));
            __half2 msg  = __hmul2(filt, u2h2(hx));
            atomicAdd(&aggf[r6 * DIM + dd],     __low2float(msg));
            atomicAdd(&aggf[r6 * DIM + dd + 1], __high2float(msg));
        }
    }
    __syncthreads();

    // ---- normalize (mean) + fp16 convert
    {
        int e0 = t * 8;
        int nd = e0 >> 7, col = e0 & 127;
        float inv = 1.0f / (float)max(pref[nd + 1] - pref[nd], 1);
        ushort8v o;
#pragma unroll
        for (int j = 0; j < 8; ++j) o[j] = f2h(aggf[e0 + j] * inv);
        *(ushort8v*)&aggh[nd][col] = o;
    }
    __syncthreads();

    // ---- GEMM1: U[64,256] = [xh | aggh] @ W3; wave wv owns cols wv*16+l15
    int wv = wid, q = lane >> 4, l15 = lane & 15;
    int col = wv * 16 + l15;
    f32x4 acc[4];
#pragma unroll
    for (int mt = 0; mt < 4; ++mt) acc[mt] = (f32x4){0.f, 0.f, 0.f, 0.f};
    for (int kc = 0; kc < 8; ++kc) {
        f16x8 a[4];
#pragma unroll
        for (int mt = 0; mt < 4; ++mt) {
            int row = mt * 16 + l15;
            if (kc < 4) a[mt] = *(const f16x8*)&xh[(n0 + row) * DIM + kc * 32 + q * 8];
            else        a[mt] = *(const f16x8*)&aggh[row][(kc - 4) * 32 + q * 8];
        }
        f16x8 b = *(const f16x8*)&w3t[col * 256 + kc * 32 + q * 8];
#pragma unroll
        for (int mt = 0; mt < 4; ++mt)
            acc[mt] = __builtin_amdgcn_mfma_f32_16x16x32_f16(a[mt], b, acc[mt], 0, 0, 0);
    }

    // ---- bias + LN stats (two-stage: intra-16-lane shfl, then 64-thread sum)
    float b3v = b3[col], gv = gamma[col], bvv = beta[col];
#pragma unroll
    for (int mt = 0; mt < 4; ++mt) {
        float s_[4], q_[4];
#pragma unroll
        for (int reg = 0; reg < 4; ++reg) {
            float v = acc[mt][reg] + b3v;
            acc[mt][reg] = v;
            s_[reg] = v; q_[reg] = v * v;
        }
#pragma unroll
        for (int off = 1; off < 16; off <<= 1) {
#pragma unroll
            for (int reg = 0; reg < 4; ++reg) {
                s_[reg] += __shfl_xor(s_[reg], off, 64);
                q_[reg] += __shfl_xor(q_[reg], off, 64);
            }
        }
        if (l15 == 0) {
#pragma unroll
            for (int reg = 0; reg < 4; ++reg) {
                int r = mt * 16 + q * 4 + reg;
                part_s[wv][r] = s_[reg];
                part_q[wv][r] = q_[reg];
            }
        }
    }
    __syncthreads();
    if (t < 64) {
        float st = 0.f, qt = 0.f;
#pragma unroll
        for (int w = 0; w < 16; ++w) { st += part_s[w][t]; qt += part_q[w][t]; }
        float mu = st * (1.0f / 256.0f);
        float var = qt * (1.0f / 256.0f) - mu * mu;
        tot_mu[t] = mu;
        tot_rs[t] = rsqrtf(var + LN_EPS);
    }
    __syncthreads();

    // ---- LN + SiLU -> fp16 act in LDS (A-operand layout [m][k])
#pragma unroll
    for (int mt = 0; mt < 4; ++mt)
#pragma unroll
        for (int reg = 0; reg < 4; ++reg) {
            int r = mt * 16 + q * 4 + reg;
            float un = (acc[mt][reg] - tot_mu[r]) * tot_rs[r] * gv + bvv;
            float act = un / (1.0f + expf(-un));
            a_lds[r][col] = f2h(act);
        }
    __syncthreads();

    // ---- GEMM2: out[64,128] = act @ W4; 32 (mt,nt) tiles over 16 waves
    int nt = wv & 7, mtb = (wv >> 3) * 2;
    int col2 = nt * 16 + l15;
    f32x4 acc2[2];
    acc2[0] = (f32x4){0.f, 0.f, 0.f, 0.f};
    acc2[1] = (f32x4){0.f, 0.f, 0.f, 0.f};
    for (int kc = 0; kc < 8; ++kc) {
        f16x8 b = *(const f16x8*)&w4t[col2 * 256 + kc * 32 + q * 8];
#pragma unroll
        for (int m2 = 0; m2 < 2; ++m2) {
            f16x8 a = *(const f16x8*)&a_lds[(mtb + m2) * 16 + l15][kc * 32 + q * 8];
            acc2[m2] = __builtin_amdgcn_mfma_f32_16x16x32_f16(a, b, acc2[m2], 0, 0, 0);
        }
    }
    float b4v = b4[col2];
#pragma unroll
    for (int m2 = 0; m2 < 2; ++m2)
#pragma unroll
        for (int reg = 0; reg < 4; ++reg) {
            int node = n0 + (mtb + m2) * 16 + q * 4 + reg;
            out[node * DIM + col2] = acc2[m2][reg] + b4v;
        }
}

// ---------------------------------------------------------------------------
extern "C" void kernel_launch(void* const* d_in, const int* in_sizes, int n_in,
                              void* d_out, int out_size, void* d_ws, size_t ws_size,
                              hipStream_t stream) {
    const float* x     = (const float*)d_in[0];
    const float* h     = (const float*)d_in[1];
    const int*   ei    = (const int*)d_in[2];
    const float* W1    = (const float*)d_in[4];
    const float* b1    = (const float*)d_in[5];
    const float* W2    = (const float*)d_in[6];
    const float* b2    = (const float*)d_in[7];
    const float* W3    = (const float*)d_in[8];
    const float* b3    = (const float*)d_in[9];
    const float* gamma = (const float*)d_in[10];
    const float* beta  = (const float*)d_in[11];
    const float* W4    = (const float*)d_in[12];
    const float* b4    = (const float*)d_in[13];
    float* out = (float*)d_out;
    int nE = in_sizes[2] / 2;

    char* ws = (char*)d_ws;
    unsigned short* Tb2  = (unsigned short*)ws; ws += (size_t)TK * 256 * 2;       // 1 MB (pair table)
    unsigned short* w3t  = (unsigned short*)ws; ws += (size_t)HID * HID * 2;      // 128 KB
    unsigned short* w4t  = (unsigned short*)ws; ws += (size_t)DIM * HID * 2;      // 64 KB
    unsigned short* xh   = (unsigned short*)ws; ws += (size_t)BN_NODES * DIM * 2; // 4 MB
    int*   counts     = (int*)ws;          ws += (size_t)BN_NODES * 4;
    int*   offsets    = (int*)ws;          ws += (size_t)(BN_NODES + 128) * 4;
    int*   bin_cursor = (int*)ws;          ws += 256 * 4;
    uint2* staging    = (uint2*)ws;        ws += (size_t)nE * 8;                  // 4 MB

    int histBlocks = (nE + 255) / 256;
    int binABlocks = (nE + EPB - 1) / EPB;
    hipMemsetAsync(counts, 0, (size_t)BN_NODES * 4, stream);
    prep_kernel<<<1376 + histBlocks, 256, 0, stream>>>(W1, b1, W2, b2, W3, W4, h, ei,
                                                       Tb2, w3t, w4t, xh, counts, nE);
    scan_kernel<<<1, 1024, 0, stream>>>(counts, offsets, bin_cursor);
    binA_kernel<<<binABlocks, 256, 0, stream>>>(ei, x, bin_cursor, staging, nE);
    agg_node_kernel<<<256, 1024, 0, stream>>>(staging, offsets, Tb2, xh,
                                              w3t, b3, gamma, beta, w4t, b4, out);
}

// Round 9
// 185.289 us; speedup vs baseline: 3.0550x; 3.0550x over previous
//
#include <hip/hip_runtime.h>
#include <hip/hip_fp16.h>
#include <math.h>

// Problem constants (fixed by the reference)
#define BN_NODES 16384     // B*N
#define DIM 128            // D
#define HID 256            // H
#define TK 2048            // distance-table knots
#define TRANGE 32.0f
#define TSTEP (TRANGE / (float)TK)   // 1/64
#define TINV  ((float)TK / TRANGE)   // 64
#define LN_EPS 1e-5f
#define EPB 4096           // edges per block in binA
#define CAPB 3072          // staging capacity per bin (mean 2048, +22 sigma)

typedef _Float16 f16x8 __attribute__((ext_vector_type(8)));
typedef __attribute__((ext_vector_type(4))) float f32x4;
typedef __attribute__((ext_vector_type(8))) unsigned short ushort8v;

__device__ __forceinline__ unsigned short f2h(float f) {
    _Float16 h = (_Float16)f;          // v_cvt_f16_f32, RNE
    return *(unsigned short*)&h;
}
__device__ __forceinline__ __half2 u2h2(unsigned int u) {
    union { unsigned int u; __half2 h; } c; c.u = u; return c.h;
}

// ---------------------------------------------------------------------------
// K1 "prep": blocks 0..255 build interleaved fp16 filter table
//   Tb2[k][pair p] = (A_{2p}, A_{2p+1}, D_{2p}, D_{2p+1}), A=T[k], D=T[k+1]-T[k]
//   -> ONE dwordx2 gather per edge-lane does the full interpolation.
// 256..319 transpose W3 -> w3t[n][k] fp16; 320..351 W4 -> w4t[n][k];
// 352..1375 h -> xh fp16; 1376..1376+hb-1 histogram; last block: cursor init.
__global__ __launch_bounds__(256) void prep_kernel(
        const float* __restrict__ W1, const float* __restrict__ b1,
        const float* __restrict__ W2, const float* __restrict__ b2,
        const float* __restrict__ W3, const float* __restrict__ W4,
        const float* __restrict__ h, const int* __restrict__ ei,
        unsigned short* __restrict__ Tb2, unsigned short* __restrict__ w3t,
        unsigned short* __restrict__ w4t, unsigned short* __restrict__ xh,
        int* __restrict__ counts, int* __restrict__ bin_cursor, int nE) {
    __shared__ float smem[9 * 256 + 9 * 128];   // 13.5 KB, role-dependent
    int bid = blockIdx.x, t = threadIdx.x;
    int hb = (nE + 255) >> 8;
    if (bid < 256) {
        float* a    = smem;            // [9][256]  (knots k0..k0+8 incl. boundary)
        float* part = smem + 9 * 256;  // [9][128]
        int k0 = bid * 8;
        float w1 = W1[t], bb = b1[t];
#pragma unroll
        for (int k = 0; k < 9; ++k) {
            float dist = (float)(k0 + k) * TSTEP;
            float z = dist * w1 + bb;
            a[k * 256 + t] = z / (1.0f + expf(-z));
        }
        __syncthreads();
        int hg = t >> 7, d = t & 127;
        float acc[9] = {0.f,0.f,0.f,0.f,0.f,0.f,0.f,0.f,0.f};
        for (int hh = 0; hh < 128; ++hh) {
            int hidx = hg * 128 + hh;
            float w = W2[hidx * DIM + d];
#pragma unroll
            for (int k = 0; k < 9; ++k) acc[k] += a[k * 256 + hidx] * w;
        }
        if (hg == 1) {
#pragma unroll
            for (int k = 0; k < 9; ++k) part[k * 128 + d] = acc[k];
        }
        __syncthreads();
        if (hg == 0) {
            float bd = b2[d];
            float v[9];
#pragma unroll
            for (int k = 0; k < 9; ++k) v[k] = acc[k] + part[k * 128 + d] + bd;
#pragma unroll
            for (int k = 0; k < 8; ++k) {
                unsigned int base = (unsigned int)(k0 + k) * 256u + (unsigned int)((d >> 1) * 4 + (d & 1));
                Tb2[base]     = f2h(v[k]);              // value
                Tb2[base + 2] = f2h(v[k + 1] - v[k]);   // delta
            }
        }
    } else if (bid < 320) {
        float* s = smem;   // [32][33]
        int tid = bid - 256, tr = tid >> 3, tc = tid & 7;
        int lr = t >> 5, lc = t & 31;
#pragma unroll
        for (int rep = 0; rep < 4; ++rep) {
            int k = tr * 32 + rep * 8 + lr, n = tc * 32 + lc;
            s[lc * 33 + rep * 8 + lr] = W3[k * 256 + n];
        }
        __syncthreads();
#pragma unroll
        for (int rep = 0; rep < 4; ++rep) {
            int n = tc * 32 + rep * 8 + lr, k = tr * 32 + lc;
            w3t[n * 256 + k] = f2h(s[(rep * 8 + lr) * 33 + lc]);
        }
    } else if (bid < 352) {
        float* s = smem;
        int tid = bid - 320, tr = tid >> 2, tc = tid & 3;
        int lr = t >> 5, lc = t & 31;
#pragma unroll
        for (int rep = 0; rep < 4; ++rep) {
            int k = tr * 32 + rep * 8 + lr, n = tc * 32 + lc;
            s[lc * 33 + rep * 8 + lr] = W4[k * 128 + n];
        }
        __syncthreads();
#pragma unroll
        for (int rep = 0; rep < 4; ++rep) {
            int n = tc * 32 + rep * 8 + lr, k = tr * 32 + lc;
            w4t[n * 256 + k] = f2h(s[(rep * 8 + lr) * 33 + lc]);
        }
    } else if (bid < 1376) {
        int i0 = (bid - 352) * 2048 + t * 8;
        float4 v0 = *(const float4*)&h[i0];
        float4 v1 = *(const float4*)&h[i0 + 4];
        ushort8v o;
        o[0] = f2h(v0.x); o[1] = f2h(v0.y); o[2] = f2h(v0.z); o[3] = f2h(v0.w);
        o[4] = f2h(v1.x); o[5] = f2h(v1.y); o[6] = f2h(v1.z); o[7] = f2h(v1.w);
        *(ushort8v*)&xh[i0] = o;
    } else if (bid < 1376 + hb) {
        int e = (bid - 1376) * 256 + t;
        if (e < nE) atomicAdd(&counts[ei[e]], 1);
    } else {
        bin_cursor[t] = t * CAPB;   // fixed per-bin staging layout (no scan needed)
    }
}

// ---------------------------------------------------------------------------
// K2: bin scatter + edge precompute. LDS counting-sort 4096-edge chunks into
// 256 bins (bin = row>>6); at write-out compute dist -> knot k and fp16 frac,
// emit uint2 (r<<16|c, k<<16|frac_bits) to the bin's fixed staging region
// [bin*CAPB, ...). (Per-bin bursty writes avoid the 13x write amplification
// of random 4B scatter across non-coherent XCD L2s.)
__global__ __launch_bounds__(256) void binA_kernel(
        const int* __restrict__ ei, const float* __restrict__ x,
        int* __restrict__ bin_cursor, uint2* __restrict__ staging, int nE) {
    __shared__ int cnt[256];
    __shared__ int pre[256];
    __shared__ int gbase[256];
    __shared__ unsigned int rec[EPB];   // 16 KB
    int t = threadIdx.x;
    int e0 = blockIdx.x * EPB;
    int m = min(EPB, nE - e0);
    cnt[t] = 0;
    __syncthreads();
    unsigned int code[16];
    int rk[16], bn[16];
#pragma unroll
    for (int j = 0; j < 16; ++j) {
        int idx = j * 256 + t;
        rk[j] = -1; bn[j] = 0; code[j] = 0;
        if (idx < m) {
            int e = e0 + idx;
            int r = ei[e], c = ei[nE + e];
            code[j] = ((unsigned int)r << 16) | (unsigned int)c;
            bn[j] = r >> 6;
            rk[j] = atomicAdd(&cnt[bn[j]], 1);
        }
    }
    __syncthreads();
    int v = cnt[t];
    pre[t] = v;
    __syncthreads();
    for (int off = 1; off < 256; off <<= 1) {
        int add = (t >= off) ? pre[t - off] : 0;
        __syncthreads();
        pre[t] += add;
        __syncthreads();
    }
    int excl = pre[t] - v;
    __syncthreads();
    pre[t] = excl;
    gbase[t] = atomicAdd(&bin_cursor[t], v);
    __syncthreads();
#pragma unroll
    for (int j = 0; j < 16; ++j)
        if (rk[j] >= 0) rec[pre[bn[j]] + rk[j]] = code[j];
    __syncthreads();
    for (int i = t; i < m; i += 256) {
        unsigned int cd = rec[i];
        int b = (int)(cd >> 22);            // row >> 6
        int r = (int)(cd >> 16);
        int c = (int)(cd & 0xffffu);
        float dx = x[r * 3 + 0] - x[c * 3 + 0];
        float dy = x[r * 3 + 1] - x[c * 3 + 1];
        float dz = x[r * 3 + 2] - x[c * 3 + 2];
        float u = sqrtf(dx * dx + dy * dy + dz * dz) * TINV;
        int k = min((int)u, TK - 2);
        float frac = u - (float)k;
        uint2 o;
        o.x = cd;
        o.y = ((unsigned int)k << 16) | (unsigned int)f2h(frac);
        int idx = gbase[b] + (i - pre[b]);
        if (idx < (b + 1) * CAPB) staging[idx] = o;   // 22-sigma guard
    }
}

// ---------------------------------------------------------------------------
// K3 "mega": bin-grain fusion WITHOUT LDS atomics (R8's 1e7-bank-conflict
// fp32 atomic accumulation replaced by counting-sort reorder + register
// accumulation). One block per bin (64 nodes, 1024 threads, 16 waves).
// Phase 0: per-node prefix from counts (wave-0 shfl scan).
// Phase 1: staging slice -> LDS CSR order (1 dword scatter per edge).
// Phase 2: wave owns 4 nodes; R7-proven gather loop (lrec broadcast + xh
// dword + Tb2 dwordx2 pair-table gather, hfma2, fp32 flush per 4 edges).
// Phase 3: MFMA GEMM1 -> LN -> SiLU -> GEMM2 -> out (R8-verified tail).
__global__ __launch_bounds__(1024, 4) void mega_kernel(
        const uint2* __restrict__ staging, const int* __restrict__ counts,
        const unsigned short* __restrict__ Tb2, const unsigned short* __restrict__ xh,
        const unsigned short* __restrict__ w3t, const float* __restrict__ b3,
        const float* __restrict__ gamma, const float* __restrict__ beta,
        const unsigned short* __restrict__ w4t, const float* __restrict__ b4,
        float* __restrict__ out) {
    __shared__ uint2 lrec[CAPB];                            // 24 KB
    __shared__ int pref[65];
    __shared__ int cur[64];
    __shared__ __align__(16) unsigned short aggh[64][136];  // 17 KB (272B stride)
    __shared__ __align__(16) unsigned short a_lds[64][264]; // 33 KB (528B stride)
    __shared__ float part_s[16][64], part_q[16][64];        // 8 KB
    __shared__ float tot_mu[64], tot_rs[64];

    int t = threadIdx.x;
    int bin = blockIdx.x;
    int n0 = bin * 64;

    // ---- phase 0: per-node exclusive prefix within bin
    if (t < 64) {
        int c = counts[n0 + t];
        int s = c;
#pragma unroll
        for (int off = 1; off < 64; off <<= 1) {
            int v = __shfl_up(s, off, 64);
            if (t >= off) s += v;
        }
        pref[t + 1] = s;
        cur[t] = s - c;
        if (t == 0) pref[0] = 0;
    }
    __syncthreads();
    int total = min(pref[64], CAPB);
    long base = (long)bin * CAPB;

    // ---- phase 1: staging -> LDS records in CSR order
    for (int i = t; i < total; i += 1024) {
        uint2 sr = staging[base + i];
        int r6 = (int)(sr.x >> 16) - n0;
        int pos = atomicAdd(&cur[r6], 1);
        uint2 o;
        o.x = (sr.x & 0xffffu) | (sr.y & 0xffff0000u);   // c | k<<16
        o.y = (sr.y & 0xffffu) * 0x10001u;               // frac2 (both halves)
        lrec[pos] = o;
    }
    __syncthreads();

    int wid = t >> 6, lane = t & 63, dd = lane * 2;

    // ---- phase 2: wave wid owns nodes wid*4 .. wid*4+3; register accumulate
#pragma unroll
    for (int jj = 0; jj < 4; ++jj) {
        int j = wid * 4 + jj;
        int off0 = pref[j], off1 = pref[j + 1];
        float a0 = 0.f, a1 = 0.f;
        int i = off0;
        for (; i + 4 <= off1; i += 4) {
            __half2 acch = __float2half2_rn(0.f);
#pragma unroll
            for (int u = 0; u < 4; ++u) {
                uint2 e = lrec[i + u];                      // LDS broadcast (free)
                int c = (int)(e.x & 0xffffu);
                int k = (int)(e.x >> 16);
                unsigned int hx = *(const unsigned int*)&xh[c * DIM + dd];
                uint2 tb = *(const uint2*)&Tb2[(k << 8) + lane * 4];
                __half2 filt = __hfma2(u2h2(tb.y), u2h2(e.y), u2h2(tb.x));
                acch = __hfma2(u2h2(hx), filt, acch);
            }
            a0 += __low2float(acch);
            a1 += __high2float(acch);
        }
        {
            __half2 acch = __float2half2_rn(0.f);
            for (; i < off1; ++i) {
                uint2 e = lrec[i];
                int c = (int)(e.x & 0xffffu);
                int k = (int)(e.x >> 16);
                unsigned int hx = *(const unsigned int*)&xh[c * DIM + dd];
                uint2 tb = *(const uint2*)&Tb2[(k << 8) + lane * 4];
                __half2 filt = __hfma2(u2h2(tb.y), u2h2(e.y), u2h2(tb.x));
                acch = __hfma2(u2h2(hx), filt, acch);
            }
            a0 += __low2float(acch);
            a1 += __high2float(acch);
        }
        float inv = 1.0f / (float)max(off1 - off0, 1);
        unsigned int packed = (unsigned int)f2h(a0 * inv)
                            | ((unsigned int)f2h(a1 * inv) << 16);
        *(unsigned int*)&aggh[j][dd] = packed;
    }
    __syncthreads();

    // ---- phase 3: GEMM1: U[64,256] = [xh | aggh] @ W3; wave owns col wv*16+l15
    int wv = wid, q = lane >> 4, l15 = lane & 15;
    int col = wv * 16 + l15;
    f32x4 acc[4];
#pragma unroll
    for (int mt = 0; mt < 4; ++mt) acc[mt] = (f32x4){0.f, 0.f, 0.f, 0.f};
    for (int kc = 0; kc < 8; ++kc) {
        f16x8 a[4];
#pragma unroll
        for (int mt = 0; mt < 4; ++mt) {
            int row = mt * 16 + l15;
            if (kc < 4) a[mt] = *(const f16x8*)&xh[(n0 + row) * DIM + kc * 32 + q * 8];
            else        a[mt] = *(const f16x8*)&aggh[row][(kc - 4) * 32 + q * 8];
        }
        f16x8 b = *(const f16x8*)&w3t[col * 256 + kc * 32 + q * 8];
#pragma unroll
        for (int mt = 0; mt < 4; ++mt)
            acc[mt] = __builtin_amdgcn_mfma_f32_16x16x32_f16(a[mt], b, acc[mt], 0, 0, 0);
    }

    // bias + LN stats (intra-16-lane shfl, then cross-wave LDS sum)
    float b3v = b3[col], gv = gamma[col], bvv = beta[col];
#pragma unroll
    for (int mt = 0; mt < 4; ++mt) {
        float s_[4], q_[4];
#pragma unroll
        for (int reg = 0; reg < 4; ++reg) {
            float v = acc[mt][reg] + b3v;
            acc[mt][reg] = v;
            s_[reg] = v; q_[reg] = v * v;
        }
#pragma unroll
        for (int off = 1; off < 16; off <<= 1) {
#pragma unroll
            for (int reg = 0; reg < 4; ++reg) {
                s_[reg] += __shfl_xor(s_[reg], off, 64);
                q_[reg] += __shfl_xor(q_[reg], off, 64);
            }
        }
        if (l15 == 0) {
#pragma unroll
            for (int reg = 0; reg < 4; ++reg) {
                int r = mt * 16 + q * 4 + reg;
                part_s[wv][r] = s_[reg];
                part_q[wv][r] = q_[reg];
            }
        }
    }
    __syncthreads();
    if (t < 64) {
        float st = 0.f, qt = 0.f;
#pragma unroll
        for (int w = 0; w < 16; ++w) { st += part_s[w][t]; qt += part_q[w][t]; }
        float mu = st * (1.0f / 256.0f);
        float var = qt * (1.0f / 256.0f) - mu * mu;
        tot_mu[t] = mu;
        tot_rs[t] = rsqrtf(var + LN_EPS);
    }
    __syncthreads();

    // LN + SiLU -> fp16 act in LDS (A-operand layout [m][k])
#pragma unroll
    for (int mt = 0; mt < 4; ++mt)
#pragma unroll
        for (int reg = 0; reg < 4; ++reg) {
            int r = mt * 16 + q * 4 + reg;
            float un = (acc[mt][reg] - tot_mu[r]) * tot_rs[r] * gv + bvv;
            float act = un / (1.0f + expf(-un));
            a_lds[r][col] = f2h(act);
        }
    __syncthreads();

    // GEMM2: out[64,128] = act @ W4; 32 (mt,nt) tiles over 16 waves
    int nt = wv & 7, mtb = (wv >> 3) * 2;
    int col2 = nt * 16 + l15;
    f32x4 acc2[2];
    acc2[0] = (f32x4){0.f, 0.f, 0.f, 0.f};
    acc2[1] = (f32x4){0.f, 0.f, 0.f, 0.f};
    for (int kc = 0; kc < 8; ++kc) {
        f16x8 b = *(const f16x8*)&w4t[col2 * 256 + kc * 32 + q * 8];
#pragma unroll
        for (int m2 = 0; m2 < 2; ++m2) {
            f16x8 a = *(const f16x8*)&a_lds[(mtb + m2) * 16 + l15][kc * 32 + q * 8];
            acc2[m2] = __builtin_amdgcn_mfma_f32_16x16x32_f16(a, b, acc2[m2], 0, 0, 0);
        }
    }
    float b4v = b4[col2];
#pragma unroll
    for (int m2 = 0; m2 < 2; ++m2)
#pragma unroll
        for (int reg = 0; reg < 4; ++reg) {
            int node = n0 + (mtb + m2) * 16 + q * 4 + reg;
            out[node * DIM + col2] = acc2[m2][reg] + b4v;
        }
}

// ---------------------------------------------------------------------------
extern "C" void kernel_launch(void* const* d_in, const int* in_sizes, int n_in,
                              void* d_out, int out_size, void* d_ws, size_t ws_size,
                              hipStream_t stream) {
    const float* x     = (const float*)d_in[0];
    const float* h     = (const float*)d_in[1];
    const int*   ei    = (const int*)d_in[2];
    const float* W1    = (const float*)d_in[4];
    const float* b1    = (const float*)d_in[5];
    const float* W2    = (const float*)d_in[6];
    const float* b2    = (const float*)d_in[7];
    const float* W3    = (const float*)d_in[8];
    const float* b3    = (const float*)d_in[9];
    const float* gamma = (const float*)d_in[10];
    const float* beta  = (const float*)d_in[11];
    const float* W4    = (const float*)d_in[12];
    const float* b4    = (const float*)d_in[13];
    float* out = (float*)d_out;
    int nE = in_sizes[2] / 2;

    char* ws = (char*)d_ws;
    unsigned short* Tb2  = (unsigned short*)ws; ws += (size_t)TK * 256 * 2;       // 1 MB (pair table)
    unsigned short* w3t  = (unsigned short*)ws; ws += (size_t)HID * HID * 2;      // 128 KB
    unsigned short* w4t  = (unsigned short*)ws; ws += (size_t)DIM * HID * 2;      // 64 KB
    unsigned short* xh   = (unsigned short*)ws; ws += (size_t)BN_NODES * DIM * 2; // 4 MB
    int*   counts     = (int*)ws;          ws += (size_t)BN_NODES * 4;
    int*   bin_cursor = (int*)ws;          ws += 256 * 4;
    uint2* staging    = (uint2*)ws;        ws += (size_t)256 * CAPB * 8;          // 6 MB

    int histBlocks = (nE + 255) / 256;
    int binABlocks = (nE + EPB - 1) / EPB;
    hipMemsetAsync(counts, 0, (size_t)BN_NODES * 4, stream);
    prep_kernel<<<1376 + histBlocks + 1, 256, 0, stream>>>(W1, b1, W2, b2, W3, W4, h, ei,
                                                           Tb2, w3t, w4t, xh, counts,
                                                           bin_cursor, nE);
    binA_kernel<<<binABlocks, 256, 0, stream>>>(ei, x, bin_cursor, staging, nE);
    mega_kernel<<<256, 1024, 0, stream>>>(staging, counts, Tb2, xh,
                                          w3t, b3, gamma, beta, w4t, b4, out);
}